// Round 9
// baseline (35.112 us; speedup 1.0000x reference)
//
#include <hip/hip_runtime.h>

#define HW  (1024u*1024u)
#define CHW (2u*HW)
#define MAXP 65536u
#define LABEL_OFF 1048576u
#define SCORE_OFF 1572864u
#define NINF (-3.0e38f)

__device__ __forceinline__ float max3f(float a, float b, float c) {
    return fmaxf(fmaxf(a, b), c);
}

// ---- A: 7x7 NMS mask + per-chunk count ----
// 1024 blocks, XCD-swizzled; block = one 16-row stripe of one image = one chunk.
// 4-row supersteps: ONE barrier per 4 rows; prefetch issued post-barrier so the
// barrier's vmcnt(0) drain hits loads issued a full superstep earlier (~free).
__global__ __launch_bounds__(256, 4) void mask_kernel(const float* __restrict__ map,
                                                      unsigned* __restrict__ bits32,
                                                      unsigned* __restrict__ chunkCount) {
    __shared__ float4 rowbuf[2][4][258];       // [parity][rowInSuperstep][col4+pads]
    __shared__ unsigned sred[4];
    int bid0 = blockIdx.x;
    int bid = (bid0 & 7) * 128 + (bid0 >> 3);  // XCD swizzle (bijective: 1024 % 8 == 0)
    int tid = threadIdx.x;
    int stripe = bid & 63;
    int img = bid >> 6;                        // b*2 + c
    int r0 = stripe << 4;
    int lane = tid & 63, wv = tid >> 6;
    const float4* __restrict__ base = (const float4*)(map + ((size_t)img << 20));
    const float4 ninf4 = make_float4(NINF, NINF, NINF, NINF);

    if (tid < 16) {                            // NINF pads at [*][*][0] and [*][*][257]
        rowbuf[(tid >> 3) & 1][(tid >> 1) & 3][(tid & 1) * 257] = ninf4;
    }

    // column-validity nibble (cols 6..1017 valid)
    int c0 = tid * 4;
    int cvm = 0;
    #pragma unroll
    for (int j = 0; j < 4; ++j) {
        int cc = c0 + j;
        if (cc >= 6 && cc <= 1017) cvm |= (1 << j);
    }

    // rolling 18-slot window: input row q -> slot (q - r0 + 3) mod 18
    float4 w[18];
    #pragma unroll
    for (int k = 0; k < 14; ++k) {             // rows r0-3 .. r0+10
        int rr = r0 - 3 + k;
        w[k] = ((unsigned)rr < 1024u) ? base[rr * 256 + tid] : ninf4;
    }

    unsigned cnt = 0;

    #pragma unroll
    for (int s = 0; s < 4; ++s) {              // superstep: rows r0+4s .. r0+4s+3
        // ---- vm compute for 2 pairs; write to LDS (registers die at store) ----
        #pragma unroll
        for (int q = 0; q < 2; ++q) {
            const int o = 4 * s + 2 * q;       // pair rows rA = r0+o, rB = rA+1
            float4 s0 = w[(o + 0) % 18], s1 = w[(o + 1) % 18];
            float4 s2 = w[(o + 2) % 18], s3 = w[(o + 3) % 18];
            float4 s4 = w[(o + 4) % 18], s5 = w[(o + 5) % 18];
            float4 s6 = w[(o + 6) % 18], s7 = w[(o + 7) % 18];
            float4 c6, vmA, vmB;
            c6.x = fmaxf(max3f(s1.x, s2.x, s3.x), max3f(s4.x, s5.x, s6.x));
            c6.y = fmaxf(max3f(s1.y, s2.y, s3.y), max3f(s4.y, s5.y, s6.y));
            c6.z = fmaxf(max3f(s1.z, s2.z, s3.z), max3f(s4.z, s5.z, s6.z));
            c6.w = fmaxf(max3f(s1.w, s2.w, s3.w), max3f(s4.w, s5.w, s6.w));
            vmA.x = fmaxf(c6.x, s0.x); vmB.x = fmaxf(c6.x, s7.x);
            vmA.y = fmaxf(c6.y, s0.y); vmB.y = fmaxf(c6.y, s7.y);
            vmA.z = fmaxf(c6.z, s0.z); vmB.z = fmaxf(c6.z, s7.z);
            vmA.w = fmaxf(c6.w, s0.w); vmB.w = fmaxf(c6.w, s7.w);
            rowbuf[s & 1][2 * q][tid + 1]     = vmA;
            rowbuf[s & 1][2 * q + 1][tid + 1] = vmB;
        }
        __syncthreads();

        // ---- post-barrier prefetch: consumed at superstep s+2's vm phase ----
        if (s < 2) {
            #pragma unroll
            for (int k = 0; k < 4; ++k) {
                int rr = r0 + 11 + 4 * s + k;
                w[(14 + 4 * s + k) % 18] = ((unsigned)rr < 1024u) ? base[rr * 256 + tid]
                                                                  : ninf4;
            }
        }

        // ---- flags phase: re-read vm rows from LDS, classify, pack, store ----
        #pragma unroll
        for (int q = 0; q < 2; ++q) {
            const int o = 4 * s + 2 * q;
            int rA = r0 + o;
            float4 VA = rowbuf[s & 1][2 * q][tid + 1];
            float4 LA = rowbuf[s & 1][2 * q][tid];
            float4 RA = rowbuf[s & 1][2 * q][tid + 2];
            float4 VB = rowbuf[s & 1][2 * q + 1][tid + 1];
            float4 LB = rowbuf[s & 1][2 * q + 1][tid];
            float4 RB = rowbuf[s & 1][2 * q + 1][tid + 2];

            float mA0 = max3f(max3f(LA.y, LA.z, LA.w),  max3f(VA.x, VA.y, VA.z), VA.w);
            float mA1 = max3f(max3f(LA.z, LA.w, VA.x),  max3f(VA.y, VA.z, VA.w), RA.x);
            float mA2 = max3f(max3f(LA.w, VA.x, VA.y),  max3f(VA.z, VA.w, RA.x), RA.y);
            float mA3 = max3f(max3f(VA.x, VA.y, VA.z),  max3f(VA.w, RA.x, RA.y), RA.z);
            float mB0 = max3f(max3f(LB.y, LB.z, LB.w),  max3f(VB.x, VB.y, VB.z), VB.w);
            float mB1 = max3f(max3f(LB.z, LB.w, VB.x),  max3f(VB.y, VB.z, VB.w), RB.x);
            float mB2 = max3f(max3f(LB.w, VB.x, VB.y),  max3f(VB.z, VB.w, RB.x), RB.y);
            float mB3 = max3f(max3f(VB.x, VB.y, VB.z),  max3f(VB.w, RB.x, RB.y), RB.z);

            float4 ctrA = w[(o + 3) % 18], ctrB = w[(o + 4) % 18];
            int fA0 = (ctrA.x == mA0) & (ctrA.x > 0.5f);
            int fA1 = (ctrA.y == mA1) & (ctrA.y > 0.5f);
            int fA2 = (ctrA.z == mA2) & (ctrA.z > 0.5f);
            int fA3 = (ctrA.w == mA3) & (ctrA.w > 0.5f);
            int fB0 = (ctrB.x == mB0) & (ctrB.x > 0.5f);
            int fB1 = (ctrB.y == mB1) & (ctrB.y > 0.5f);
            int fB2 = (ctrB.z == mB2) & (ctrB.z > 0.5f);
            int fB3 = (ctrB.w == mB3) & (ctrB.w > 0.5f);
            int nibA = (fA0 | (fA1 << 1) | (fA2 << 2) | (fA3 << 3)) & cvm;
            int nibB = (fB0 | (fB1 << 1) | (fB2 << 2) | (fB3 << 3)) & cvm;
            int rowokA = (rA >= 6) & (rA <= 1017);
            int rowokB = ((rA + 1) >= 6) & ((rA + 1) <= 1017);
            nibA = rowokA ? nibA : 0;
            nibB = rowokB ? nibB : 0;

            cnt += (unsigned)(__popc((unsigned)nibA) + __popc((unsigned)nibB));

            // assemble u32 half-words: 8-lane group g -> cols 32g..32g+31 of the row
            unsigned vA = (unsigned)nibA << ((lane & 7) * 4);
            unsigned vB = (unsigned)nibB << ((lane & 7) * 4);
            vA |= __shfl_xor(vA, 1, 64); vB |= __shfl_xor(vB, 1, 64);
            vA |= __shfl_xor(vA, 2, 64); vB |= __shfl_xor(vB, 2, 64);
            vA |= __shfl_xor(vA, 4, 64); vB |= __shfl_xor(vB, 4, 64);
            if ((lane & 7) == 0) {
                // u32 index = img*32768 + row*32 + wv*8 + (lane>>3)
                size_t wbase = ((size_t)img << 15) + ((size_t)rA << 5) + wv * 8 + (lane >> 3);
                bits32[wbase]      = vA;
                bits32[wbase + 32] = vB;        // row rA+1
            }
        }
    }

    // per-chunk count (block == one chunk; chunk linear index == bid)
    for (int off = 32; off; off >>= 1) cnt += __shfl_down(cnt, off, 64);
    if (lane == 0) sred[wv] = cnt;
    __syncthreads();
    if (tid == 0) chunkCount[bid] = sred[0] + sred[1] + sred[2] + sred[3];
}

// ---- B: fused scan + ordered scatter + tail padding (float32 outputs) ----
// Same XCD swizzle as mask so this block's bits reads hit the producing XCD's L2.
__global__ __launch_bounds__(256) void scan_scatter(const float* __restrict__ map,
                                                    const unsigned long long* __restrict__ bits,
                                                    const unsigned* __restrict__ chunkCount,
                                                    float* __restrict__ out) {
    int bid0 = blockIdx.x;
    int blk = (bid0 & 7) * 128 + (bid0 >> 3);   // match mask's chunk->XCD mapping
    int b = blk >> 7, cib = blk & 127;
    int tid = threadIdx.x;
    int lane = tid & 63, wv = tid >> 6;

    __shared__ unsigned long long sw[4];
    __shared__ unsigned sbase, stotal;
    __shared__ int wsum[4];

    // packed reduce: low32 = sum over chunks < cib (base), high32 = sum over all (total)
    unsigned cc = (tid < 128) ? chunkCount[b * 128 + tid] : 0u;
    unsigned long long v = ((tid < cib) ? (unsigned long long)cc : 0ull)
                         | ((unsigned long long)cc << 32);
    for (int off = 32; off; off >>= 1) v += __shfl_down(v, off, 64);
    if (lane == 0) sw[wv] = v;
    __syncthreads();
    if (tid == 0) {
        unsigned long long t = sw[0] + sw[1] + sw[2] + sw[3];
        sbase  = (unsigned)t;
        stotal = (unsigned)(t >> 32);
    }

    // own word + intra-block exclusive prefix of popcounts (shfl scan)
    unsigned long long wd = bits[(size_t)blk * 256 + tid];
    int cnt = __popcll(wd);
    int incl = cnt;
    #pragma unroll
    for (int off = 1; off < 64; off <<= 1) {
        int n = __shfl_up(incl, off, 64);
        if (lane >= off) incl += n;
    }
    if (lane == 63) wsum[wv] = incl;
    __syncthreads();                            // also publishes sbase/stotal

    int wpre = 0;
    #pragma unroll
    for (int k = 0; k < 4; ++k) if (k < wv) wpre += wsum[k];
    unsigned base = sbase + (unsigned)wpre + (unsigned)(incl - cnt);
    unsigned wib = ((unsigned)cib) * 256u + (unsigned)tid;       // word idx in batch

    unsigned long long m = wd;
    unsigned n = 0;
    while (m) {
        int bit = __builtin_ctzll(m);
        m &= m - 1;
        unsigned slot = base + n;
        n++;
        if (slot < MAXP) {
            unsigned flat = wib * 64u + (unsigned)bit;   // < 2^21
            unsigned c = flat >> 20;
            unsigned h = (flat >> 10) & 1023u;
            unsigned wcol = flat & 1023u;
            float score = map[(size_t)b * CHW + flat];
            unsigned o = b * MAXP + slot;
            out[2u * o]         = (float)wcol;           // x
            out[2u * o + 1]     = (float)h;              // y
            out[LABEL_OFF + o]  = (float)(c + 1u);       // label
            out[SCORE_OFF + o]  = score;                 // score
        }
    }

    // tail padding: this block owns slots [cib*512, cib*512+512)
    unsigned total = stotal;
    #pragma unroll
    for (int k = 0; k < 2; ++k) {
        unsigned slot = ((unsigned)cib) * 512u + (unsigned)tid + (unsigned)k * 256u;
        if (slot >= total) {                    // slot < 65536 by construction
            unsigned o = b * MAXP + slot;
            float2 neg1; neg1.x = -1.0f; neg1.y = -1.0f;
            ((float2*)out)[o]   = neg1;          // coords (x,y) = -1
            out[LABEL_OFF + o]  = 0.0f;
            out[SCORE_OFF + o]  = 0.0f;
        }
    }
}

extern "C" void kernel_launch(void* const* d_in, const int* in_sizes, int n_in,
                              void* d_out, int out_size, void* d_ws, size_t ws_size,
                              hipStream_t stream) {
    const float* map = (const float*)d_in[0];
    float* out = (float*)d_out;
    unsigned long long* bits = (unsigned long long*)d_ws;        // 262144 u64 = 2 MB
    unsigned* chunkCount = (unsigned*)((char*)d_ws + 2097152);   // 1024 u32

    mask_kernel<<<1024, 256, 0, stream>>>(map, (unsigned*)d_ws, chunkCount);
    scan_scatter<<<1024, 256, 0, stream>>>(map, bits, chunkCount, out);
}